// Round 1
// 145.402 us; speedup vs baseline: 1.0380x; 1.0380x over previous
//
#include <hip/hip_runtime.h>
#include <cstddef>

#define S_TOK 4096
#define CDIM 256
#define NHEADS 4
#define HDIM 64
#define LSK 72   // ushort stride for attention LDS rows
#define LDA 36   // ushort stride for GEMM LDS tiles (32 k + 4 pad)
#define LDY 264  // float stride for LN buffer
#define LOG2E 1.44269504f

typedef __attribute__((ext_vector_type(8))) short short8;
typedef __attribute__((ext_vector_type(4))) float floatx4;

__device__ inline unsigned short f2bf(float f) {
  union { float f; unsigned u; } v;
  v.f = f;
  unsigned r = v.u + 0x7fff + ((v.u >> 16) & 1);  // round-to-nearest-even
  return (unsigned short)(r >> 16);
}
__device__ inline float bf2f(unsigned short u) {
  union { unsigned u; float f; } v;
  v.u = ((unsigned)u) << 16;
  return v.f;
}
// pack two floats to bf16x2 (low = a). Single HW instr either way (m240:
// no builtin on gfx950 -> inline asm; RNE rounding identical to f2bf).
__device__ inline unsigned pack_bf16(float a, float b) {
#if __has_builtin(__builtin_amdgcn_cvt_pk_bf16_f32)
  typedef __bf16 bf16x2 __attribute__((ext_vector_type(2)));
  union { bf16x2 v; unsigned u; } r;
  r.v = __builtin_amdgcn_cvt_pk_bf16_f32(a, b);
  return r.u;
#else
  unsigned r;
  asm("v_cvt_pk_bf16_f32 %0, %1, %2" : "=v"(r) : "v"(a), "v"(b));
  return r;
#endif
}

// gfx950 cross-lane row swaps (CDNA4). Both operands are read-write:
//  permlane32_swap: d' = [d.r0 d.r1 | s.r0 s.r1], s' = [d.r2 d.r3 | s.r2 s.r3]
//  permlane16_swap: d' = [d.r0 s.r0 d.r2 s.r2],   s' = [d.r1 s.r1 d.r3 s.r3]
// (rows = 16-lane groups)
__device__ inline void pl32swap(unsigned& a, unsigned& b) {
  asm("v_permlane32_swap_b32 %0, %1" : "+v"(a), "+v"(b));
}
__device__ inline void pl16swap(unsigned& a, unsigned& b) {
  asm("v_permlane16_swap_b32 %0, %1" : "+v"(a), "+v"(b));
}

// ---------------- Kernel 1: fused QKV GEMM, fp32 inputs staged to bf16 -------
// Block: 64 tokens x 64 dh-channels x {q,k,v} (3 B-tiles share one A-tile).
// A staged directly from x (b,C,S) fp32: k-slab = 32 contiguous rows.
// B staged directly from in_proj_w fp32. q prescale = (1/8)*log2e.
__global__ __launch_bounds__(256) void qkv_gemm_kernel(
    const float* __restrict__ x, const float* __restrict__ ipw,
    const float* __restrict__ ipb, unsigned short* __restrict__ q16,
    unsigned short* __restrict__ k16, unsigned short* __restrict__ vt16) {
  __shared__ __align__(16) unsigned short As[64 * LDA];     // [tok_l][k_l]
  __shared__ __align__(16) unsigned short Bs[3][64 * LDA];  // [slab][dh_l][k_l]
  const int tid = threadIdx.x;
  const int wave = tid >> 6, lane = tid & 63;
  const int quad = lane >> 4, l16 = lane & 15;
  const int n0 = blockIdx.x * 64;   // dh-block within slab (0..192)
  const int tok0 = blockIdx.y * 64; // token base within batch
  const int b = blockIdx.z;

  // A staging: thread = (channel c_l 0..31, token-octet t8 0..7)
  const int c_l = tid >> 3, t8 = tid & 7;
  const float* gx = x + (((size_t)(b * CDIM + c_l)) << 12) + tok0 + t8 * 8;
  unsigned short* wa = &As[(t8 * 8) * LDA + c_l];

  // B staging: thread = (row rr 0..63, k-chunk c4 0..3) x 3 slabs
  const int rr = tid >> 2, c4 = tid & 3;
  const float* gw0 = ipw + ((size_t)(n0 + rr)) * CDIM + c4 * 8;
  unsigned short* wb0 = &Bs[0][rr * LDA + c4 * 8];

  floatx4 acc[3][4];
#pragma unroll
  for (int s = 0; s < 3; ++s)
#pragma unroll
    for (int nt = 0; nt < 4; ++nt) acc[s][nt] = (floatx4){0.f, 0.f, 0.f, 0.f};

  // prefetch ks=0
  float4 a0 = *(const float4*)(gx);
  float4 a1 = *(const float4*)(gx + 4);
  float4 bp[3][2];
#pragma unroll
  for (int s = 0; s < 3; ++s) {
    bp[s][0] = *(const float4*)(gw0 + (size_t)s * 256 * CDIM);
    bp[s][1] = *(const float4*)(gw0 + (size_t)s * 256 * CDIM + 4);
  }

  for (int ks = 0; ks < 8; ++ks) {
    __syncthreads();
    // A -> LDS: 8 bf16 scalar writes (pairs via HW pack)
    {
      unsigned p;
      p = pack_bf16(a0.x, a0.y);
      wa[0 * LDA] = (unsigned short)p; wa[1 * LDA] = (unsigned short)(p >> 16);
      p = pack_bf16(a0.z, a0.w);
      wa[2 * LDA] = (unsigned short)p; wa[3 * LDA] = (unsigned short)(p >> 16);
      p = pack_bf16(a1.x, a1.y);
      wa[4 * LDA] = (unsigned short)p; wa[5 * LDA] = (unsigned short)(p >> 16);
      p = pack_bf16(a1.z, a1.w);
      wa[6 * LDA] = (unsigned short)p; wa[7 * LDA] = (unsigned short)(p >> 16);
    }
    // B -> LDS: 2x 8B writes per slab
#pragma unroll
    for (int s = 0; s < 3; ++s) {
      uint2 u0, u1;
      u0.x = pack_bf16(bp[s][0].x, bp[s][0].y);
      u0.y = pack_bf16(bp[s][0].z, bp[s][0].w);
      u1.x = pack_bf16(bp[s][1].x, bp[s][1].y);
      u1.y = pack_bf16(bp[s][1].z, bp[s][1].w);
      unsigned short* w = wb0 + s * 64 * LDA;
      *(uint2*)w = u0;
      *(uint2*)(w + 4) = u1;
    }
    __syncthreads();
    if (ks < 7) {  // prefetch next k-slab
      const float* gxn = gx + ((size_t)((ks + 1) * 32) << 12);
      a0 = *(const float4*)(gxn);
      a1 = *(const float4*)(gxn + 4);
#pragma unroll
      for (int s = 0; s < 3; ++s) {
        const float* g = gw0 + (size_t)s * 256 * CDIM + (ks + 1) * 32;
        bp[s][0] = *(const float4*)(g);
        bp[s][1] = *(const float4*)(g + 4);
      }
    }
    short8 af = *(const short8*)&As[(wave * 16 + l16) * LDA + quad * 8];
#pragma unroll
    for (int s = 0; s < 3; ++s)
#pragma unroll
      for (int nt = 0; nt < 4; ++nt) {
        short8 bf = *(const short8*)&Bs[s][(nt * 16 + l16) * LDA + quad * 8];
        acc[s][nt] = __builtin_amdgcn_mfma_f32_16x16x32_bf16(af, bf, acc[s][nt], 0, 0, 0);
      }
  }

  // epilogue
  const float qsc = 0.125f * LOG2E;
#pragma unroll
  for (int nt = 0; nt < 4; ++nt) {
    int cb = n0 + nt * 16 + l16;       // channel within slab, 0..255
    int h = cb >> 6, dh = cb & 63;
    float bq = ipb[cb], bk = ipb[256 + cb], bv = ipb[512 + cb];
    size_t base = ((size_t)(b * NHEADS + h)) * S_TOK;
#pragma unroll
    for (int r = 0; r < 4; ++r) {
      int tok = tok0 + wave * 16 + quad * 4 + r;
      q16[(base + tok) * HDIM + dh] = f2bf((acc[0][nt][r] + bq) * qsc);
      k16[(base + tok) * HDIM + dh] = f2bf(acc[1][nt][r] + bk);
    }
    int tokv = tok0 + wave * 16 + quad * 4;
    uint2 u;
    u.x = pack_bf16(acc[2][nt][0] + bv, acc[2][nt][1] + bv);
    u.y = pack_bf16(acc[2][nt][2] + bv, acc[2][nt][3] + bv);
    *(uint2*)&vt16[(base * 0 + ((size_t)(b * NHEADS + h) * HDIM + dh)) * S_TOK + tokv] = u;
  }
}

// ---------------- Kernel 2: flash attention, S^T trick, in-register P --------
// 4 waves x 64 q-rows each (mt=4), 64-key tiles, 4-way key split.
// P never touches LDS: exp(S^T) lives lane-local per q-row; PV A-fragments are
// built with cvt_pk + permlane32_swap + permlane16_swap (see pl*swap comments):
//   per kt: A=pack(p0,p1) B=pack(p2,p3); for kt-pair: swap32 then swap16 on
//   (A_ktA,A_ktB) yields fragment dwords {dw0,dw2}; same on B pair -> {dw1,dw3}.
// K/V double-buffered in LDS, ONE barrier per tile; next-tile global loads
// issued before compute, LDS writes after (vmcnt drain hidden under MFMA).
__global__ __launch_bounds__(256) void attn_kernel(
    const unsigned short* __restrict__ q16,
    const unsigned short* __restrict__ k16,
    const unsigned short* __restrict__ vt16,
    unsigned short* __restrict__ op, float* __restrict__ lp) {
  __shared__ __align__(16) unsigned short Ks[2][64 * LSK];  // [buf][key][d]
  __shared__ __align__(16) unsigned short Vt[2][64 * LSK];  // [buf][d][key]

  const int tid = threadIdx.x;
  const int wave = tid >> 6;
  const int lane = tid & 63;
  const int quad = lane >> 4;
  const int l16 = lane & 15;
  const int bh = blockIdx.y;
  const int q0 = blockIdx.x * 256;
  const int split = blockIdx.z;
  const int kt0 = split * 16;

  short8 qf[4][2];
#pragma unroll
  for (int mt = 0; mt < 4; ++mt) {
    const unsigned short* qg =
        q16 + ((size_t)bh * S_TOK + q0 + wave * 64 + mt * 16 + l16) * HDIM + quad * 8;
    qf[mt][0] = *(const short8*)(qg);
    qf[mt][1] = *(const short8*)(qg + 32);
  }

  const int sr = tid >> 3, scc = tid & 7;
  const unsigned short* kg = k16 + ((size_t)bh * S_TOK + sr) * HDIM + scc * 8;
  const unsigned short* vg = vt16 + ((size_t)bh * HDIM + sr) * S_TOK + scc * 8;

  floatx4 O[4][4];
  float lsum[4] = {0.f, 0.f, 0.f, 0.f};
#pragma unroll
  for (int mt = 0; mt < 4; ++mt)
#pragma unroll
    for (int nt = 0; nt < 4; ++nt) O[mt][nt] = (floatx4){0.f, 0.f, 0.f, 0.f};

  // prologue: tile 0 -> buf 0
  uint4 k0r = *(const uint4*)(kg + (size_t)kt0 * 64 * HDIM);
  uint4 k1r = *(const uint4*)(kg + (size_t)kt0 * 64 * HDIM + 32 * HDIM);
  uint4 v0r = *(const uint4*)(vg + kt0 * 64);
  uint4 v1r = *(const uint4*)(vg + kt0 * 64 + (size_t)32 * S_TOK);
  {
    unsigned short* kw = &Ks[0][sr * LSK + scc * 8];
    unsigned short* vw = &Vt[0][sr * LSK + scc * 8];
    *(uint4*)kw = k0r;
    *(uint4*)(kw + 32 * LSK) = k1r;
    *(uint4*)vw = v0r;
    *(uint4*)(vw + 32 * LSK) = v1r;
  }
  __syncthreads();

  for (int t = 0; t < 16; ++t) {
    const int cur = t & 1;
    if (t < 15) {  // issue next-tile loads now; write LDS after compute
      const unsigned short* kgn = kg + (size_t)(kt0 + t + 1) * 64 * HDIM;
      const unsigned short* vgn = vg + (kt0 + t + 1) * 64;
      k0r = *(const uint4*)(kgn);
      k1r = *(const uint4*)(kgn + 32 * HDIM);
      v0r = *(const uint4*)(vgn);
      v1r = *(const uint4*)(vgn + (size_t)32 * S_TOK);
    }
    const unsigned short* Kb = Ks[cur];
    const unsigned short* Vb = Vt[cur];

#pragma unroll
    for (int c = 0; c < 2; ++c) {  // 32-key chunk = kt pair (2c, 2c+1)
      short8 kfA0 = *(const short8*)(&Kb[((c * 2) * 16 + l16) * LSK + quad * 8]);
      short8 kfA1 = *(const short8*)(&Kb[((c * 2) * 16 + l16) * LSK + 32 + quad * 8]);
      short8 kfB0 = *(const short8*)(&Kb[((c * 2 + 1) * 16 + l16) * LSK + quad * 8]);
      short8 kfB1 = *(const short8*)(&Kb[((c * 2 + 1) * 16 + l16) * LSK + 32 + quad * 8]);
      short8 vf[4];
#pragma unroll
      for (int nt = 0; nt < 4; ++nt)
        vf[nt] = *(const short8*)(&Vb[(nt * 16 + l16) * LSK + c * 32 + quad * 8]);
#pragma unroll
      for (int mt = 0; mt < 4; ++mt) {
        floatx4 cA = (floatx4){0.f, 0.f, 0.f, 0.f};
        cA = __builtin_amdgcn_mfma_f32_16x16x32_bf16(kfA0, qf[mt][0], cA, 0, 0, 0);
        cA = __builtin_amdgcn_mfma_f32_16x16x32_bf16(kfA1, qf[mt][1], cA, 0, 0, 0);
        floatx4 cB = (floatx4){0.f, 0.f, 0.f, 0.f};
        cB = __builtin_amdgcn_mfma_f32_16x16x32_bf16(kfB0, qf[mt][0], cB, 0, 0, 0);
        cB = __builtin_amdgcn_mfma_f32_16x16x32_bf16(kfB1, qf[mt][1], cB, 0, 0, 0);
        // exp2 of S^T: lane holds P[q=l16][key = kt*16 + quad*4 + r]
        float a0 = __builtin_amdgcn_exp2f(cA[0]);
        float a1 = __builtin_amdgcn_exp2f(cA[1]);
        float a2 = __builtin_amdgcn_exp2f(cA[2]);
        float a3 = __builtin_amdgcn_exp2f(cA[3]);
        float b0 = __builtin_amdgcn_exp2f(cB[0]);
        float b1 = __builtin_amdgcn_exp2f(cB[1]);
        float b2 = __builtin_amdgcn_exp2f(cB[2]);
        float b3 = __builtin_amdgcn_exp2f(cB[3]);
        lsum[mt] += ((a0 + a1) + (a2 + a3)) + ((b0 + b1) + (b2 + b3));
        // build PV A-fragment in-register (no LDS round-trip)
        unsigned A0 = pack_bf16(a0, a1), B0 = pack_bf16(a2, a3);
        unsigned A1 = pack_bf16(b0, b1), B1 = pack_bf16(b2, b3);
        pl32swap(A0, A1); pl16swap(A0, A1);  // A0 -> dw0 (keys 8q+0,1), A1 -> dw2 (keys 8q+4,5)
        pl32swap(B0, B1); pl16swap(B0, B1);  // B0 -> dw1 (keys 8q+2,3), B1 -> dw3 (keys 8q+6,7)
        union { uint4 u; short8 s; } pf;
        pf.u.x = A0; pf.u.y = B0; pf.u.z = A1; pf.u.w = B1;
#pragma unroll
        for (int nt = 0; nt < 4; ++nt)
          O[mt][nt] = __builtin_amdgcn_mfma_f32_16x16x32_bf16(pf.s, vf[nt], O[mt][nt], 0, 0, 0);
      }
    }

    if (t < 15) {  // stage next tile into the other buffer; single barrier
      unsigned short* kw = &Ks[cur ^ 1][sr * LSK + scc * 8];
      unsigned short* vw = &Vt[cur ^ 1][sr * LSK + scc * 8];
      *(uint4*)kw = k0r;
      *(uint4*)(kw + 32 * LSK) = k1r;
      *(uint4*)vw = v0r;
      *(uint4*)(vw + 32 * LSK) = v1r;
      __syncthreads();
    }
  }

  const int b = bh >> 2, h = bh & 3;
  unsigned short* op_s = op + (size_t)split * 2097152;
  float* lp_s = lp + (size_t)split * 32768;
#pragma unroll
  for (int mt = 0; mt < 4; ++mt) {
    float ls = lsum[mt];
    ls += __shfl_xor(ls, 16);
    ls += __shfl_xor(ls, 32);
    if (quad == 0)
      lp_s[bh * S_TOK + q0 + wave * 64 + mt * 16 + l16] = ls;
#pragma unroll
    for (int r = 0; r < 4; ++r) {
      int row = q0 + wave * 64 + mt * 16 + quad * 4 + r;
#pragma unroll
      for (int nt = 0; nt < 4; ++nt)
        op_s[((size_t)(b * S_TOK + row)) * CDIM + h * HDIM + nt * 16 + l16] =
            f2bf(O[mt][nt][r]);
    }
  }
}

// merged A-chunk: 4 ushorts = sum of 4 split partials * (1/l)
__device__ inline uint2 merge4(const unsigned short* op, size_t off, float rinv) {
  float s0 = 0.f, s1 = 0.f, s2 = 0.f, s3 = 0.f;
#pragma unroll
  for (int sp = 0; sp < 4; ++sp) {
    uint2 u = *(const uint2*)(op + (size_t)sp * 2097152 + off);
    s0 += bf2f((unsigned short)(u.x & 0xffff));
    s1 += bf2f((unsigned short)(u.x >> 16));
    s2 += bf2f((unsigned short)(u.y & 0xffff));
    s3 += bf2f((unsigned short)(u.y >> 16));
  }
  uint2 r;
  r.x = pack_bf16(s0 * rinv, s1 * rinv);
  r.y = pack_bf16(s2 * rinv, s3 * rinv);
  return r;
}

// ---------------- Kernel 3: merge + out projection + LayerNorm ---------------
// Block: 32 tokens x 256 c_out (full); B staged directly from fp32 out_w.
__global__ __launch_bounds__(256) void out_ln_gemm_kernel(
    const unsigned short* __restrict__ op, const float* __restrict__ lp,
    const float* __restrict__ ow, const float* __restrict__ obias,
    const float* __restrict__ lng, const float* __restrict__ lnb,
    float* __restrict__ out) {
  __shared__ __align__(16) unsigned short As[32 * LDA];
  __shared__ __align__(16) unsigned short Bs[256 * LDA];
  __shared__ __align__(16) float ys[32 * LDY];
  __shared__ float rsum[128];  // [tok_l][h]
  const int tid = threadIdx.x;
  const int wave = tid >> 6, lane = tid & 63;
  const int quad = lane >> 4, l16 = lane & 15;
  const int tok0 = blockIdx.x * 32;  // global token (b folded)

  if (tid < 128) {
    int t = tid >> 2, h = tid & 3;
    int bb = tok0 >> 12;
    int idx = (bb * 4 + h) * 4096 + (tok0 & 4095) + t;
    rsum[tid] =
        1.0f / (lp[idx] + lp[32768 + idx] + lp[65536 + idx] + lp[98304 + idx]);
  }
  __syncthreads();

  // A: 32 rows x 8 4-ushort chunks
  const int ar = tid >> 3, ac = tid & 7;
  const size_t abase = (size_t)(tok0 + ar) * CDIM + ac * 4;
  unsigned short* wAp = &As[ar * LDA + ac * 4];
  // B: 64-row groups x 4, thread covers rows rr+64i, floats c4*8..+7
  const int rr = tid >> 2, c4 = tid & 3;
  const float* gB = ow + (size_t)rr * CDIM + c4 * 8;
  unsigned short* wBp = &Bs[rr * LDA + c4 * 8];

  floatx4 acc[2][4];
#pragma unroll
  for (int mt = 0; mt < 2; ++mt)
#pragma unroll
    for (int nt = 0; nt < 4; ++nt) acc[mt][nt] = (floatx4){0.f, 0.f, 0.f, 0.f};

  uint2 ap = merge4(op, abase, rsum[(ar << 2) + (ac >> 4)]);  // ks=0: h = ac*4>>6 = 0 for ac<16 -> ac>>4==0
  float4 bpf[4][2];
#pragma unroll
  for (int i = 0; i < 4; ++i) {
    bpf[i][0] = *(const float4*)(gB + (size_t)i * 64 * CDIM);
    bpf[i][1] = *(const float4*)(gB + (size_t)i * 64 * CDIM + 4);
  }

  for (int ks = 0; ks < 8; ++ks) {
    __syncthreads();
    *(uint2*)wAp = ap;
#pragma unroll
    for (int i = 0; i < 4; ++i) {
      uint2 u0, u1;
      u0.x = pack_bf16(bpf[i][0].x, bpf[i][0].y);
      u0.y = pack_bf16(bpf[i][0].z, bpf[i][0].w);
      u1.x = pack_bf16(bpf[i][1].x, bpf[i][1].y);
      u1.y = pack_bf16(bpf[i][1].z, bpf[i][1].w);
      unsigned short* w = wBp + i * 64 * LDA;
      *(uint2*)w = u0;
      *(uint2*)(w + 4) = u1;
    }
    __syncthreads();
    if (ks < 7) {
      int off = (ks + 1) * 32;
      int ch = off + ac * 4;  // channel of this thread's A chunk
      ap = merge4(op, abase + off, rsum[(ar << 2) + (ch >> 6)]);
#pragma unroll
      for (int i = 0; i < 4; ++i) {
        bpf[i][0] = *(const float4*)(gB + (size_t)i * 64 * CDIM + off);
        bpf[i][1] = *(const float4*)(gB + (size_t)i * 64 * CDIM + off + 4);
      }
    }
    short8 af[2], bf[4];
#pragma unroll
    for (int mt = 0; mt < 2; ++mt)
      af[mt] = *(const short8*)&As[(mt * 16 + l16) * LDA + quad * 8];
#pragma unroll
    for (int nt = 0; nt < 4; ++nt)
      bf[nt] = *(const short8*)&Bs[(wave * 64 + nt * 16 + l16) * LDA + quad * 8];
#pragma unroll
    for (int mt = 0; mt < 2; ++mt)
#pragma unroll
      for (int nt = 0; nt < 4; ++nt)
        acc[mt][nt] = __builtin_amdgcn_mfma_f32_16x16x32_bf16(af[mt], bf[nt], acc[mt][nt], 0, 0, 0);
  }

#pragma unroll
  for (int mt = 0; mt < 2; ++mt)
#pragma unroll
    for (int nt = 0; nt < 4; ++nt) {
      int c = wave * 64 + nt * 16 + l16;
      float bo = obias[c];
#pragma unroll
      for (int r = 0; r < 4; ++r)
        ys[(mt * 16 + quad * 4 + r) * LDY + c] = acc[mt][nt][r] + bo;
    }
  __syncthreads();

  // LayerNorm: 8 lanes per token
  const int gtok = tid >> 3, l8 = tid & 7;
  float sum = 0.f, ssq = 0.f;
#pragma unroll
  for (int i = 0; i < 32; ++i) {
    float v = ys[gtok * LDY + i * 8 + l8];
    sum += v;
    ssq += v * v;
  }
  sum += __shfl_xor(sum, 1); ssq += __shfl_xor(ssq, 1);
  sum += __shfl_xor(sum, 2); ssq += __shfl_xor(ssq, 2);
  sum += __shfl_xor(sum, 4); ssq += __shfl_xor(ssq, 4);
  float mu = sum * (1.f / 256.f);
  float var = ssq * (1.f / 256.f) - mu * mu;
  float rstd = rsqrtf(var + 1e-5f);
  const int b2 = tok0 >> 12;
  const int sl = (tok0 & 4095) + gtok;
#pragma unroll
  for (int i = 0; i < 32; ++i) {
    int c = i * 8 + l8;
    float v = ys[gtok * LDY + c];
    out[(((size_t)(b2 * CDIM + c)) << 12) + sl] = (v - mu) * rstd * lng[c] + lnb[c];
  }
}

extern "C" void kernel_launch(void* const* d_in, const int* in_sizes, int n_in,
                              void* d_out, int out_size, void* d_ws, size_t ws_size,
                              hipStream_t stream) {
  const float* x = (const float*)d_in[0];
  const float* ipw = (const float*)d_in[1];
  const float* ipb = (const float*)d_in[2];
  const float* ow = (const float*)d_in[3];
  const float* ob = (const float*)d_in[4];
  const float* lng = (const float*)d_in[5];
  const float* lnb = (const float*)d_in[6];
  float* out = (float*)d_out;
  // workspace (ushort units), total ~29.9 MiB:
  unsigned short* q16 = (unsigned short*)d_ws;       // 2097152
  unsigned short* k16 = q16 + 2097152;               // 2097152
  unsigned short* vt16 = k16 + 2097152;              // 2097152
  unsigned short* op = vt16 + 2097152;               // 4 x 2097152 (ab-layout partials)
  float* lp = (float*)(op + 8388608);                // 4 x 32768 fp32

  qkv_gemm_kernel<<<dim3(4, 64, 2), 256, 0, stream>>>(x, ipw, ipb, q16, k16, vt16);
  attn_kernel<<<dim3(16, 8, 4), 256, 0, stream>>>(q16, k16, vt16, op, lp);
  out_ln_gemm_kernel<<<256, 256, 0, stream>>>(op, lp, ow, ob, lng, lnb, out);
}